// Round 1
// baseline (919.795 us; speedup 1.0000x reference)
//
#include <hip/hip_runtime.h>

#define CC 128
#define HH 80
#define WW 256
#define NSL 320                 // 4*80 slices
#define TRI_PAD_TOT 33280       // sum of row lengths padded to multiple of 4
#define DISP_OFF 0
#define CONF_OFF 81920
#define OCC_OFF  163840
#define CV_OFF   245760
#define CVD_OFF  21217280
#define NU_C (1.0f/512.0f)
#define MU_C (1.0f/512.0f)

// start offset of padded triangular row i: rows padded to multiple of 4 floats
__device__ __forceinline__ int rs_of(int i) {
  int q = i >> 2, m = i & 3;
  return 4*i + 8*q*q - 8*q + 4*m*q;
}

// ---------------- cost-volume GEMM with fused LayerNorm ----------------
// grid (2,2,320): 128x128 tile of slice z=b*80+h. k-split 64 -> 64KB dyn LDS.
__global__ __launch_bounds__(256, 2)
void cv_kernel(const float* __restrict__ feat, const float* __restrict__ lnw,
               const float* __restrict__ lnb, float* __restrict__ cv_out) {
  extern __shared__ float sm[];
  float* As = sm;              // [64][128] k-major
  float* Bs = sm + 64*128;
  __shared__ float rmean[256], rrstd[256], lwS[128], lbS[128];
  const int t = threadIdx.x;
  const int z = blockIdx.z, b = z / HH, h = z % HH;
  const int i0 = blockIdx.y * 128, j0 = blockIdx.x * 128;
  if (t < 128) { lwS[t] = lnw[t]; lbS[t] = lnb[t]; }
  {
    const int isA = (t < 128);
    const int row = isA ? (i0 + t) : (j0 + (t - 128));
    const int bb  = isA ? b : (b + 4);
    const float* p = feat + ((size_t)bb*CC*HH + (size_t)h)*WW + row;
    float s = 0.f, s2 = 0.f;
    for (int c = 0; c < CC; ++c) {
      float v = p[(size_t)c*HH*WW];
      s += v; s2 = fmaf(v, v, s2);
    }
    float mu  = s * (1.f/CC);
    float var = fmaf(-mu, mu, s2 * (1.f/CC));
    rmean[t] = mu; rrstd[t] = rsqrtf(var + 1e-5f);
  }
  float acc[64];
  #pragma unroll
  for (int q = 0; q < 64; ++q) acc[q] = 0.f;
  const int ty = t >> 4, tx = t & 15;
  const size_t baseA = ((size_t)b*CC*HH + (size_t)h)*WW + i0;
  const size_t baseB = ((size_t)(b+4)*CC*HH + (size_t)h)*WW + j0;
  for (int kc = 0; kc < 2; ++kc) {
    __syncthreads();
    #pragma unroll
    for (int r = 0; r < 32; ++r) {
      int idx = r*256 + t;
      int kl = idx >> 7, il = idx & 127;
      int c = kc*64 + kl;
      float a  = feat[baseA + (size_t)c*HH*WW + il];
      As[kl*128 + il] = (a - rmean[il]) * rrstd[il] * lwS[c] + lbS[c];
      float bv = feat[baseB + (size_t)c*HH*WW + il];
      Bs[kl*128 + il] = (bv - rmean[128 + il]) * rrstd[128 + il] * lwS[c] + lbS[c];
    }
    __syncthreads();
    #pragma unroll 2
    for (int kl = 0; kl < 64; ++kl) {
      float4 a0 = *(const float4*)&As[kl*128 + ty*8];
      float4 a1 = *(const float4*)&As[kl*128 + ty*8 + 4];
      float4 b0 = *(const float4*)&Bs[kl*128 + tx*4];        // 2-way bank alias: free
      float4 b1 = *(const float4*)&Bs[kl*128 + 64 + tx*4];
      float av[8] = {a0.x,a0.y,a0.z,a0.w,a1.x,a1.y,a1.z,a1.w};
      float bv[8] = {b0.x,b0.y,b0.z,b0.w,b1.x,b1.y,b1.z,b1.w};
      #pragma unroll
      for (int rr = 0; rr < 8; ++rr)
        #pragma unroll
        for (int qq = 0; qq < 8; ++qq)
          acc[rr*8+qq] = fmaf(av[rr], bv[qq], acc[rr*8+qq]);
    }
  }
  #pragma unroll
  for (int rr = 0; rr < 8; ++rr) {
    int row = i0 + ty*8 + rr;
    size_t obase = ((size_t)z*256 + row)*256;
    *(float4*)&cv_out[obase + j0 + tx*4] =
        make_float4(acc[rr*8+0],acc[rr*8+1],acc[rr*8+2],acc[rr*8+3]);
    *(float4*)&cv_out[obase + j0 + 64 + tx*4] =
        make_float4(acc[rr*8+4],acc[rr*8+5],acc[rr*8+6],acc[rr*8+7]);
  }
}

// ---------------- downsampled cost volume (h,i strided by 2) ----------------
// grid 160: one 128x128 slice per block (z = b*40+hd)
__global__ __launch_bounds__(256, 2)
void cvd_kernel(const float* __restrict__ feat, const float* __restrict__ lnw,
                const float* __restrict__ lnb, float* __restrict__ cvd_out) {
  extern __shared__ float sm[];
  float* As = sm; float* Bs = sm + 64*128;
  __shared__ float rmean[256], rrstd[256], lwS[128], lbS[128];
  const int t = threadIdx.x;
  const int z = blockIdx.x, b = z / 40, hd = z % 40, h = 2*hd;
  if (t < 128) { lwS[t] = lnw[t]; lbS[t] = lnb[t]; }
  {
    const int isA = (t < 128);
    const int rowd = isA ? t : (t - 128);
    const int bb = isA ? b : (b + 4);
    const float* p = feat + ((size_t)bb*CC*HH + (size_t)h)*WW + 2*rowd;
    float s = 0.f, s2 = 0.f;
    for (int c = 0; c < CC; ++c) { float v = p[(size_t)c*HH*WW]; s += v; s2 = fmaf(v,v,s2); }
    float mu  = s * (1.f/CC);
    float var = fmaf(-mu, mu, s2 * (1.f/CC));
    rmean[t] = mu; rrstd[t] = rsqrtf(var + 1e-5f);
  }
  float acc[64];
  #pragma unroll
  for (int q = 0; q < 64; ++q) acc[q] = 0.f;
  const int ty = t >> 4, tx = t & 15;
  const size_t baseA = ((size_t)b*CC*HH + (size_t)h)*WW;
  const size_t baseB = ((size_t)(b+4)*CC*HH + (size_t)h)*WW;
  for (int kc = 0; kc < 2; ++kc) {
    __syncthreads();
    #pragma unroll
    for (int r = 0; r < 32; ++r) {
      int idx = r*256 + t;
      int kl = idx >> 7, il = idx & 127;
      int c = kc*64 + kl;
      float a  = feat[baseA + (size_t)c*HH*WW + 2*il];
      As[kl*128 + il] = (a - rmean[il]) * rrstd[il] * lwS[c] + lbS[c];
      float bv = feat[baseB + (size_t)c*HH*WW + 2*il];
      Bs[kl*128 + il] = (bv - rmean[128 + il]) * rrstd[128 + il] * lwS[c] + lbS[c];
    }
    __syncthreads();
    #pragma unroll 2
    for (int kl = 0; kl < 64; ++kl) {
      float4 a0 = *(const float4*)&As[kl*128 + ty*8];
      float4 a1 = *(const float4*)&As[kl*128 + ty*8 + 4];
      float4 b0 = *(const float4*)&Bs[kl*128 + tx*4];
      float4 b1 = *(const float4*)&Bs[kl*128 + 64 + tx*4];
      float av[8] = {a0.x,a0.y,a0.z,a0.w,a1.x,a1.y,a1.z,a1.w};
      float bv[8] = {b0.x,b0.y,b0.z,b0.w,b1.x,b1.y,b1.z,b1.w};
      #pragma unroll
      for (int rr = 0; rr < 8; ++rr)
        #pragma unroll
        for (int qq = 0; qq < 8; ++qq)
          acc[rr*8+qq] = fmaf(av[rr], bv[qq], acc[rr*8+qq]);
    }
  }
  #pragma unroll
  for (int rr = 0; rr < 8; ++rr) {
    int row = ty*8 + rr;
    size_t obase = ((size_t)z*128 + row)*128;
    *(float4*)&cvd_out[obase + tx*4] =
        make_float4(acc[rr*8+0],acc[rr*8+1],acc[rr*8+2],acc[rr*8+3]);
    *(float4*)&cvd_out[obase + 64 + tx*4] =
        make_float4(acc[rr*8+4],acc[rr*8+5],acc[rr*8+6],acc[rr*8+7]);
  }
}

// ---------------- Sinkhorn (multiplicative domain, triangular E in LDS) ------
// One block (256 thr) per slice. E=exp(cv-M) lower-triangular, rows padded to 4.
// Pad row/col of the reference (attn=0) contribute exp(-M) analytically.
__global__ __launch_bounds__(256, 1)
void sink_kernel(const float* __restrict__ cvg, float* __restrict__ out) {
  extern __shared__ float pE[];            // TRI_PAD_TOT floats
  __shared__ __align__(16) float eu[260];
  __shared__ __align__(16) float ev[260];
  __shared__ float redbuf[8];
  __shared__ float Msh;
  const int t = threadIdx.x;
  const int z = blockIdx.x;
  const float* cvS = cvg + (size_t)z * (256*256);

  // pass 1: masked slice max (pads contribute 0)
  float mx = 0.f;
  for (int i = 0; i < 256; ++i) {
    float v = cvS[i*256 + t];
    if (t <= i) mx = fmaxf(mx, v);
  }
  #pragma unroll
  for (int m = 32; m; m >>= 1) mx = fmaxf(mx, __shfl_xor(mx, m, 64));
  if ((t & 63) == 0) redbuf[t >> 6] = mx;
  __syncthreads();
  if (t == 0) Msh = fmaxf(fmaxf(redbuf[0], redbuf[1]), fmaxf(redbuf[2], redbuf[3]));
  __syncthreads();
  const float M = Msh;
  const float enM = __expf(-M);

  // pass 2: build packed triangular E (zero the pad tail of each row)
  {
    int rs = 0;
    for (int i = 0; i < 256; ++i) {
      int padlen = (i & ~3) + 4;
      float v = cvS[i*256 + t];
      if (t < padlen) pE[rs + t] = (t <= i) ? __expf(v - M) : 0.f;
      rs += padlen;
    }
  }
  eu[t] = 1.f;
  if (t == 0) eu[256] = 1.f;
  __syncthreads();

  const int w = t >> 6;
  const int istart = w << 6;
  const int rs0 = rs_of(istart);
  const int rsT = rs_of(t);
  const int nb = (t >> 2) + 1;

  for (int it = 0; it < 8; ++it) {
    { // colsum -> ev   (thread t = column j; coalesced across lanes)
      float c0=0.f,c1=0.f,c2=0.f,c3=0.f;
      int rs = rs0;
      for (int i = istart; i < 256; i += 4) {
        int L = i + 4;                       // padded length of rows i..i+3
        float4 euv = *(const float4*)&eu[i];
        if (t <= i  ) c0 = fmaf(pE[rs        + t], euv.x, c0);
        if (t <= i+1) c1 = fmaf(pE[rs +   L  + t], euv.y, c1);
        if (t <= i+2) c2 = fmaf(pE[rs + 2*L  + t], euv.z, c2);
        if (t <= i+3) c3 = fmaf(pE[rs + 3*L  + t], euv.w, c3);
        rs += 4*L;
      }
      float c = ((c0+c1)+(c2+c3)) + enM * eu[256];   // pad row i=256
      float s = eu[t];
      #pragma unroll
      for (int m = 32; m; m >>= 1) s += __shfl_xor(s, m, 64);
      if ((t & 63) == 0) redbuf[w] = s;
      __syncthreads();
      float S = ((redbuf[0]+redbuf[1])+(redbuf[2]+redbuf[3])) + eu[256];
      ev[t] = NU_C / c;
      if (t == 0) ev[256] = 0.5f / (enM * S);        // pad column marginal = 1/2
      __syncthreads();
    }
    { // rowsum -> eu   (thread t = row i; contiguous packed row, float4)
      const float4* rowp = (const float4*)&pE[rsT];
      float r0=0.f,r1=0.f,r2=0.f,r3=0.f;
      for (int bk = 0; bk < nb; ++bk) {
        float4 e4  = rowp[bk];
        float4 ev4 = *(const float4*)&ev[bk*4];
        r0 = fmaf(e4.x, ev4.x, r0);
        r1 = fmaf(e4.y, ev4.y, r1);
        r2 = fmaf(e4.z, ev4.z, r2);
        r3 = fmaf(e4.w, ev4.w, r3);
      }
      float r = ((r0+r1)+(r2+r3)) + enM * ev[256];   // pad col j=256
      float s = ev[t];
      #pragma unroll
      for (int m = 32; m; m >>= 1) s += __shfl_xor(s, m, 64);
      if ((t & 63) == 0) redbuf[w] = s;
      __syncthreads();
      float S = ((redbuf[0]+redbuf[1])+(redbuf[2]+redbuf[3])) + ev[256];
      eu[t] = MU_C / r;
      if (t == 0) eu[256] = 0.5f / (enM * S);
      __syncthreads();
    }
  }

  // final: prob = E*eu*ev*512 ; per-row argmax (first max), occ, conf/corr
  {
    const float4* rowp = (const float4*)&pE[rsT];
    float occ = 0.f, vmax = -1.f;
    int jmax = 0;
    for (int bk = 0; bk < nb; ++bk) {
      float4 e4  = rowp[bk];
      float4 ev4 = *(const float4*)&ev[bk*4];
      float p0 = e4.x*ev4.x, p1 = e4.y*ev4.y, p2 = e4.z*ev4.z, p3 = e4.w*ev4.w;
      occ += ((p0+p1)+(p2+p3));
      if (p0 > vmax) { vmax = p0; jmax = bk*4;   }
      if (p1 > vmax) { vmax = p1; jmax = bk*4+1; }
      if (p2 > vmax) { vmax = p2; jmax = bk*4+2; }
      if (p3 > vmax) { vmax = p3; jmax = bk*4+3; }
    }
    const float sc = eu[t] * 512.f;
    float conf = 0.f, corr = 0.f;
    #pragma unroll
    for (int d = 0; d < 5; ++d) {
      int jp = jmax + d - 2;
      float wgt = 0.f;
      if (jp >= 0 && jp <= t) wgt = pE[rsT + jp] * ev[jp] * sc;
      conf += wgt;
      corr = fmaf(wgt, (float)jp, corr);
    }
    corr = (corr + 1e-4f) / (conf + 1e-4f);
    out[DISP_OFF + z*256 + t] = (float)t - corr;
    out[CONF_OFF + z*256 + t] = conf;
    out[OCC_OFF  + z*256 + t] = occ * sc;
  }
}

extern "C" void kernel_launch(void* const* d_in, const int* in_sizes, int n_in,
                              void* d_out, int out_size, void* d_ws, size_t ws_size,
                              hipStream_t stream) {
  (void)in_sizes; (void)n_in; (void)out_size; (void)d_ws; (void)ws_size;
  const float* feat = (const float*)d_in[0];
  const float* lnw  = (const float*)d_in[1];
  const float* lnb  = (const float*)d_in[2];
  float* out = (float*)d_out;

  (void)hipFuncSetAttribute((const void*)cv_kernel,
                            hipFuncAttributeMaxDynamicSharedMemorySize, 65536);
  (void)hipFuncSetAttribute((const void*)cvd_kernel,
                            hipFuncAttributeMaxDynamicSharedMemorySize, 65536);
  (void)hipFuncSetAttribute((const void*)sink_kernel,
                            hipFuncAttributeMaxDynamicSharedMemorySize, TRI_PAD_TOT*4);

  cv_kernel<<<dim3(2, 2, NSL), 256, 65536, stream>>>(feat, lnw, lnb, out + CV_OFF);
  cvd_kernel<<<dim3(160), 256, 65536, stream>>>(feat, lnw, lnb, out + CVD_OFF);
  sink_kernel<<<dim3(NSL), 256, TRI_PAD_TOT*4, stream>>>(out + CV_OFF, out);
}

// Round 2
// 434.380 us; speedup vs baseline: 2.1175x; 2.1175x over previous
//
#include <hip/hip_runtime.h>

#define CC 128
#define HH 80
#define WW 256
#define NSL 320                 // 4*80 slices
#define TRI_PAD_TOT 33280       // sum of row lengths padded to multiple of 4
#define DISP_OFF 0
#define CONF_OFF 81920
#define OCC_OFF  163840
#define CV_OFF   245760
#define CVD_OFF  21217280
#define NU_C (1.0f/512.0f)
#define MU_C (1.0f/512.0f)

// ---------------- cost-volume GEMM with fused LayerNorm ----------------
// grid (2,2,320): 128x128 tile of slice z=b*80+h. k-split 64 -> 64KB dyn LDS.
__global__ __launch_bounds__(256, 2)
void cv_kernel(const float* __restrict__ feat, const float* __restrict__ lnw,
               const float* __restrict__ lnb, float* __restrict__ cv_out) {
  extern __shared__ float sm[];
  float* As = sm;              // [64][128] k-major
  float* Bs = sm + 64*128;
  __shared__ __align__(16) float rmean[256];
  __shared__ __align__(16) float rrstd[256];
  __shared__ float lwS[128], lbS[128];
  const int t = threadIdx.x;
  const int z = blockIdx.z, b = z / HH, h = z % HH;
  const int i0 = blockIdx.y * 128, j0 = blockIdx.x * 128;
  if (t < 128) { lwS[t] = lnw[t]; lbS[t] = lnb[t]; }
  {
    const int isA = (t < 128);
    const int row = isA ? (i0 + t) : (j0 + (t - 128));
    const int bb  = isA ? b : (b + 4);
    const float* p = feat + ((size_t)bb*CC*HH + (size_t)h)*WW + row;
    float s = 0.f, s2 = 0.f;
    for (int c = 0; c < CC; ++c) {
      float v = p[(size_t)c*HH*WW];
      s += v; s2 = fmaf(v, v, s2);
    }
    float mu  = s * (1.f/CC);
    float var = fmaf(-mu, mu, s2 * (1.f/CC));
    rmean[t] = mu; rrstd[t] = rsqrtf(var + 1e-5f);
  }
  float acc[64];
  #pragma unroll
  for (int q = 0; q < 64; ++q) acc[q] = 0.f;
  const int ty = t >> 4, tx = t & 15;
  const size_t baseA = ((size_t)b*CC*HH + (size_t)h)*WW + i0;
  const size_t baseB = ((size_t)(b+4)*CC*HH + (size_t)h)*WW + j0;
  for (int kc = 0; kc < 2; ++kc) {
    __syncthreads();
    #pragma unroll
    for (int r = 0; r < 8; ++r) {
      int f = r*256 + t;                 // 2048 float4 per operand tile
      int kl = f >> 5, col = (f & 31)*4;
      int ch = kc*64 + kl;
      float lw = lwS[ch], lb = lbS[ch];
      float4 va = *(const float4*)&feat[baseA + (size_t)ch*HH*WW + col];
      float4 rm = *(const float4*)&rmean[col];
      float4 rr = *(const float4*)&rrstd[col];
      va.x = (va.x-rm.x)*rr.x*lw+lb; va.y = (va.y-rm.y)*rr.y*lw+lb;
      va.z = (va.z-rm.z)*rr.z*lw+lb; va.w = (va.w-rm.w)*rr.w*lw+lb;
      *(float4*)&As[kl*128 + col] = va;
      float4 vb = *(const float4*)&feat[baseB + (size_t)ch*HH*WW + col];
      float4 rm2 = *(const float4*)&rmean[128+col];
      float4 rr2 = *(const float4*)&rrstd[128+col];
      vb.x = (vb.x-rm2.x)*rr2.x*lw+lb; vb.y = (vb.y-rm2.y)*rr2.y*lw+lb;
      vb.z = (vb.z-rm2.z)*rr2.z*lw+lb; vb.w = (vb.w-rm2.w)*rr2.w*lw+lb;
      *(float4*)&Bs[kl*128 + col] = vb;
    }
    __syncthreads();
    #pragma unroll 2
    for (int kl = 0; kl < 64; ++kl) {
      float4 a0 = *(const float4*)&As[kl*128 + ty*8];
      float4 a1 = *(const float4*)&As[kl*128 + ty*8 + 4];
      float4 b0 = *(const float4*)&Bs[kl*128 + tx*4];        // 2-way bank alias: free
      float4 b1 = *(const float4*)&Bs[kl*128 + 64 + tx*4];
      float av[8] = {a0.x,a0.y,a0.z,a0.w,a1.x,a1.y,a1.z,a1.w};
      float bv[8] = {b0.x,b0.y,b0.z,b0.w,b1.x,b1.y,b1.z,b1.w};
      #pragma unroll
      for (int rr = 0; rr < 8; ++rr)
        #pragma unroll
        for (int qq = 0; qq < 8; ++qq)
          acc[rr*8+qq] = fmaf(av[rr], bv[qq], acc[rr*8+qq]);
    }
  }
  #pragma unroll
  for (int rr = 0; rr < 8; ++rr) {
    int row = i0 + ty*8 + rr;
    size_t obase = ((size_t)z*256 + row)*256;
    *(float4*)&cv_out[obase + j0 + tx*4] =
        make_float4(acc[rr*8+0],acc[rr*8+1],acc[rr*8+2],acc[rr*8+3]);
    *(float4*)&cv_out[obase + j0 + 64 + tx*4] =
        make_float4(acc[rr*8+4],acc[rr*8+5],acc[rr*8+6],acc[rr*8+7]);
  }
}

// ---------------- downsampled cost volume (h,i strided by 2) ----------------
__global__ __launch_bounds__(256, 2)
void cvd_kernel(const float* __restrict__ feat, const float* __restrict__ lnw,
                const float* __restrict__ lnb, float* __restrict__ cvd_out) {
  extern __shared__ float sm[];
  float* As = sm; float* Bs = sm + 64*128;
  __shared__ __align__(16) float rmean[256];
  __shared__ __align__(16) float rrstd[256];
  __shared__ float lwS[128], lbS[128];
  const int t = threadIdx.x;
  const int z = blockIdx.x, b = z / 40, hd = z % 40, h = 2*hd;
  if (t < 128) { lwS[t] = lnw[t]; lbS[t] = lnb[t]; }
  {
    const int isA = (t < 128);
    const int rowd = isA ? t : (t - 128);
    const int bb = isA ? b : (b + 4);
    const float* p = feat + ((size_t)bb*CC*HH + (size_t)h)*WW + 2*rowd;
    float s = 0.f, s2 = 0.f;
    for (int c = 0; c < CC; ++c) { float v = p[(size_t)c*HH*WW]; s += v; s2 = fmaf(v,v,s2); }
    float mu  = s * (1.f/CC);
    float var = fmaf(-mu, mu, s2 * (1.f/CC));
    rmean[t] = mu; rrstd[t] = rsqrtf(var + 1e-5f);
  }
  float acc[64];
  #pragma unroll
  for (int q = 0; q < 64; ++q) acc[q] = 0.f;
  const int ty = t >> 4, tx = t & 15;
  const size_t baseA = ((size_t)b*CC*HH + (size_t)h)*WW;
  const size_t baseB = ((size_t)(b+4)*CC*HH + (size_t)h)*WW;
  for (int kc = 0; kc < 2; ++kc) {
    __syncthreads();
    #pragma unroll
    for (int r = 0; r < 8; ++r) {
      int f = r*256 + t;
      int kl = f >> 5, col = (f & 31)*4;
      int ch = kc*64 + kl;
      float lw = lwS[ch], lb = lbS[ch];
      const float* pa = &feat[baseA + (size_t)ch*HH*WW + 2*col];
      float4 q0 = *(const float4*)pa;
      float4 q1 = *(const float4*)(pa + 4);
      float4 rm = *(const float4*)&rmean[col];
      float4 rr = *(const float4*)&rrstd[col];
      float4 va = make_float4((q0.x-rm.x)*rr.x*lw+lb, (q0.z-rm.y)*rr.y*lw+lb,
                              (q1.x-rm.z)*rr.z*lw+lb, (q1.z-rm.w)*rr.w*lw+lb);
      *(float4*)&As[kl*128 + col] = va;
      const float* pb = &feat[baseB + (size_t)ch*HH*WW + 2*col];
      float4 s0 = *(const float4*)pb;
      float4 s1 = *(const float4*)(pb + 4);
      float4 rm2 = *(const float4*)&rmean[128+col];
      float4 rr2 = *(const float4*)&rrstd[128+col];
      float4 vb = make_float4((s0.x-rm2.x)*rr2.x*lw+lb, (s0.z-rm2.y)*rr2.y*lw+lb,
                              (s1.x-rm2.z)*rr2.z*lw+lb, (s1.z-rm2.w)*rr2.w*lw+lb);
      *(float4*)&Bs[kl*128 + col] = vb;
    }
    __syncthreads();
    #pragma unroll 2
    for (int kl = 0; kl < 64; ++kl) {
      float4 a0 = *(const float4*)&As[kl*128 + ty*8];
      float4 a1 = *(const float4*)&As[kl*128 + ty*8 + 4];
      float4 b0 = *(const float4*)&Bs[kl*128 + tx*4];
      float4 b1 = *(const float4*)&Bs[kl*128 + 64 + tx*4];
      float av[8] = {a0.x,a0.y,a0.z,a0.w,a1.x,a1.y,a1.z,a1.w};
      float bv[8] = {b0.x,b0.y,b0.z,b0.w,b1.x,b1.y,b1.z,b1.w};
      #pragma unroll
      for (int rr = 0; rr < 8; ++rr)
        #pragma unroll
        for (int qq = 0; qq < 8; ++qq)
          acc[rr*8+qq] = fmaf(av[rr], bv[qq], acc[rr*8+qq]);
    }
  }
  #pragma unroll
  for (int rr = 0; rr < 8; ++rr) {
    int row = ty*8 + rr;
    size_t obase = ((size_t)z*128 + row)*128;
    *(float4*)&cvd_out[obase + tx*4] =
        make_float4(acc[rr*8+0],acc[rr*8+1],acc[rr*8+2],acc[rr*8+3]);
    *(float4*)&cvd_out[obase + 64 + tx*4] =
        make_float4(acc[rr*8+4],acc[rr*8+5],acc[rr*8+6],acc[rr*8+7]);
  }
}

// ---------------- Sinkhorn: 1024 threads/block, 4-way chunked reductions -----
// Thread (j = t&255, c = t>>8). Colsum: chunk c owns rows i ≡ c (mod 4).
// Rowsum/epilogue: chunk c owns float4-blocks bk ≡ c (mod 4) of row j.
// E = exp(cv - M) lower-triangular, rows padded to mult-of-4, packed in LDS.
__global__ __launch_bounds__(1024, 4)
void sink_kernel(const float* __restrict__ cvg, float* __restrict__ out) {
  extern __shared__ float pE[];            // TRI_PAD_TOT floats
  __shared__ __align__(16) float eu[260];
  __shared__ __align__(16) float ev[260];
  __shared__ float part[4][256];
  __shared__ float vmxS[4][256];
  __shared__ int   jmxS[4][256];
  __shared__ float redbuf[16];
  __shared__ float Msh;
  const int t = threadIdx.x;
  const int j = t & 255;
  const int c = t >> 8;
  const int w = t >> 6;
  const int z = blockIdx.x;
  const float* cvS = cvg + (size_t)z * 65536;

  // pass 1: cache this thread's 64 column entries in VGPRs, masked max
  float vc[64];
  float mx = 0.f;
  #pragma unroll
  for (int m = 0; m < 64; ++m) {
    int i = 4*m + c;
    vc[m] = cvS[i*256 + j];
    mx = (j <= i) ? fmaxf(mx, vc[m]) : mx;
  }
  #pragma unroll
  for (int mm = 32; mm; mm >>= 1) mx = fmaxf(mx, __shfl_xor(mx, mm, 64));
  if ((t & 63) == 0) redbuf[w] = mx;
  if (t < 256) eu[t] = 1.f;
  if (t == 0) eu[256] = 1.f;
  __syncthreads();
  if (t == 0) {
    float m2 = redbuf[0];
    #pragma unroll
    for (int q = 1; q < 16; ++q) m2 = fmaxf(m2, redbuf[q]);
    Msh = m2;
  }
  __syncthreads();
  const float M = Msh;
  const float enM = __expf(-M);

  // pass 2: build packed triangular E from registers
  {
    int rs = 4*c;                          // rs_of(row c)
    #pragma unroll
    for (int m = 0; m < 64; ++m) {
      int i = 4*m + c;
      if (j < 4*m + 4) pE[rs + j] = (j <= i) ? __expf(vc[m] - M) : 0.f;
      rs += 16*m + 16 + 4*c;
    }
  }
  __syncthreads();

  const int q4 = j >> 2, m4 = j & 3;
  const int rsR = 8*q4*q4 + 8*q4 + 4*m4*q4 + 4*m4;   // rs_of(row j)
  const int nb = q4 + 1;                              // float4 blocks in row j

  for (int it = 0; it < 8; ++it) {
    { // ---- colsum -> ev : chunk c sums rows i≡c (mod 4), i >= j ----
      int m0 = (j > c) ? ((j - c + 3) >> 2) : 0;
      int m = m0;
      int rs = 8*m*m + 8*m + 4*c*m + 4*c;
      float s0 = 0.f, s1 = 0.f;
      for (; m + 1 < 64; m += 2) {
        int i = 4*m + c;
        s0 = fmaf(pE[rs + j], eu[i], s0);
        int rs1 = rs + 16*m + 16 + 4*c;
        s1 = fmaf(pE[rs1 + j], eu[i + 4], s1);
        rs = rs1 + 16*(m + 1) + 16 + 4*c;
      }
      if (m < 64) s0 = fmaf(pE[rs + j], eu[4*m + c], s0);
      part[c][j] = s0 + s1;
      if (t < 256) {                        // overlap: S_eu reduce (eu is stable)
        float s = eu[t];
        #pragma unroll
        for (int mm = 32; mm; mm >>= 1) s += __shfl_xor(s, mm, 64);
        if ((t & 63) == 0) redbuf[w] = s;
      }
      __syncthreads();
      if (t < 256) {
        float cj = ((part[0][t] + part[1][t]) + (part[2][t] + part[3][t]))
                 + enM * eu[256];
        ev[t] = NU_C / cj;
        if (t == 0) {
          float S = ((redbuf[0] + redbuf[1]) + (redbuf[2] + redbuf[3])) + eu[256];
          ev[256] = 0.5f / (enM * S);
        }
      }
      __syncthreads();
    }
    { // ---- rowsum -> eu : chunk c sums float4 blocks bk≡c (mod 4) of row j ----
      float r0 = 0.f, r1 = 0.f, r2 = 0.f, r3 = 0.f;
      for (int bk = c; bk < nb; bk += 4) {
        float4 e4  = *(const float4*)&pE[rsR + 4*bk];
        float4 ev4 = *(const float4*)&ev[4*bk];
        r0 = fmaf(e4.x, ev4.x, r0);
        r1 = fmaf(e4.y, ev4.y, r1);
        r2 = fmaf(e4.z, ev4.z, r2);
        r3 = fmaf(e4.w, ev4.w, r3);
      }
      part[c][j] = (r0 + r1) + (r2 + r3);
      if (t < 256) {                        // S_ev reduce (ev stable now)
        float s = ev[t];
        #pragma unroll
        for (int mm = 32; mm; mm >>= 1) s += __shfl_xor(s, mm, 64);
        if ((t & 63) == 0) redbuf[w] = s;
      }
      __syncthreads();
      if (t < 256) {
        float ri = ((part[0][t] + part[1][t]) + (part[2][t] + part[3][t]))
                 + enM * ev[256];
        eu[t] = MU_C / ri;
        if (t == 0) {
          float S = ((redbuf[0] + redbuf[1]) + (redbuf[2] + redbuf[3])) + ev[256];
          eu[256] = 0.5f / (enM * S);
        }
      }
      __syncthreads();
    }
  }

  // ---- epilogue: per-row occ / argmax (first-max) / conf / corr ----
  {
    float occ = 0.f, vmax = -1.f;
    int jm = 1 << 30;
    for (int bk = c; bk < nb; bk += 4) {
      float4 e4  = *(const float4*)&pE[rsR + 4*bk];
      float4 ev4 = *(const float4*)&ev[4*bk];
      float p0 = e4.x*ev4.x, p1 = e4.y*ev4.y, p2 = e4.z*ev4.z, p3 = e4.w*ev4.w;
      occ += (p0 + p1) + (p2 + p3);
      if (p0 > vmax) { vmax = p0; jm = 4*bk;   }
      if (p1 > vmax) { vmax = p1; jm = 4*bk+1; }
      if (p2 > vmax) { vmax = p2; jm = 4*bk+2; }
      if (p3 > vmax) { vmax = p3; jm = 4*bk+3; }
    }
    part[c][j] = occ;
    vmxS[c][j] = vmax;
    jmxS[c][j] = jm;
    __syncthreads();
    if (t < 256) {
      float vb = -1.f; int jb = 1 << 30; float occT = 0.f;
      #pragma unroll
      for (int cc = 0; cc < 4; ++cc) {
        occT += part[cc][t];
        float v = vmxS[cc][t]; int jj = jmxS[cc][t];
        if (v > vb || (v == vb && jj < jb)) { vb = v; jb = jj; }
      }
      const int r = t;
      const int qq = r >> 2, mm2 = r & 3;
      const int rsT = 8*qq*qq + 8*qq + 4*mm2*qq + 4*mm2;
      const float sc = eu[r] * 512.f;
      float conf = 0.f, corr = 0.f;
      #pragma unroll
      for (int d = 0; d < 5; ++d) {
        int jp = jb + d - 2;
        float wgt = 0.f;
        if (jp >= 0 && jp <= r) wgt = pE[rsT + jp] * ev[jp] * sc;
        conf += wgt;
        corr = fmaf(wgt, (float)jp, corr);
      }
      corr = (corr + 1e-4f) / (conf + 1e-4f);
      out[DISP_OFF + z*256 + r] = (float)r - corr;
      out[CONF_OFF + z*256 + r] = conf;
      out[OCC_OFF  + z*256 + r] = occT * sc;
    }
  }
}

extern "C" void kernel_launch(void* const* d_in, const int* in_sizes, int n_in,
                              void* d_out, int out_size, void* d_ws, size_t ws_size,
                              hipStream_t stream) {
  (void)in_sizes; (void)n_in; (void)out_size; (void)d_ws; (void)ws_size;
  const float* feat = (const float*)d_in[0];
  const float* lnw  = (const float*)d_in[1];
  const float* lnb  = (const float*)d_in[2];
  float* out = (float*)d_out;

  (void)hipFuncSetAttribute((const void*)cv_kernel,
                            hipFuncAttributeMaxDynamicSharedMemorySize, 65536);
  (void)hipFuncSetAttribute((const void*)cvd_kernel,
                            hipFuncAttributeMaxDynamicSharedMemorySize, 65536);
  (void)hipFuncSetAttribute((const void*)sink_kernel,
                            hipFuncAttributeMaxDynamicSharedMemorySize, TRI_PAD_TOT*4);

  cv_kernel<<<dim3(2, 2, NSL), 256, 65536, stream>>>(feat, lnw, lnb, out + CV_OFF);
  cvd_kernel<<<dim3(160), 256, 65536, stream>>>(feat, lnw, lnb, out + CVD_OFF);
  sink_kernel<<<dim3(NSL), 1024, TRI_PAD_TOT*4, stream>>>(out + CV_OFF, out);
}

// Round 4
// 413.595 us; speedup vs baseline: 2.2239x; 1.0503x over previous
//
#include <hip/hip_runtime.h>

#define CC 128
#define HH 80
#define WW 256
#define NSL 320                 // 4*80 slices
#define TRI2_TOT 36864          // quad-uniform staggered triangle, floats (144 KB)
#define DISP_OFF 0
#define CONF_OFF 81920
#define OCC_OFF  163840
#define CV_OFF   245760
#define CVD_OFF  21217280
#define NU_C (1.0f/512.0f)
#define MU_C (1.0f/512.0f)

// Quad m (rows 4m..4m+3) all have padded length ell(m) = 4 + 32*((m+7)>>3).
// Row start S(i) = Q(m) + (i&3)*ell(m), Q(m) = 16m + 128*G(m),
// G(m) = 4q(q-1) + r*q with q=(m+7)>>3, r=(m+7)&7.
// Properties (verified): S(i) ≡ 4i (mod 32)  -> b128 row reads conflict-free;
// S(i) ≡ 0 (mod 4) -> 16B aligned; S(256) = 36864 = TRI2_TOT.
__device__ __forceinline__ int ell_of(int m) { return 4 + (((m + 7) >> 3) << 5); }
__device__ __forceinline__ int S_of(int i) {
  int m = i >> 2;
  int q = (m + 7) >> 3, r = (m + 7) & 7;
  int Q = 16*m + ((q*(q-1)) << 9) + ((r*q) << 7);
  return Q + (i & 3) * ell_of(m);
}

// ---------------- cost-volume GEMM with fused LayerNorm ----------------
__global__ __launch_bounds__(256, 2)
void cv_kernel(const float* __restrict__ feat, const float* __restrict__ lnw,
               const float* __restrict__ lnb, float* __restrict__ cv_out) {
  extern __shared__ float sm[];
  float* As = sm;              // [64][128] k-major
  float* Bs = sm + 64*128;
  __shared__ __align__(16) float rmean[256];
  __shared__ __align__(16) float rrstd[256];
  __shared__ float lwS[128], lbS[128];
  const int t = threadIdx.x;
  const int z = blockIdx.z, b = z / HH, h = z % HH;
  const int i0 = blockIdx.y * 128, j0 = blockIdx.x * 128;
  if (t < 128) { lwS[t] = lnw[t]; lbS[t] = lnb[t]; }
  {
    const int isA = (t < 128);
    const int row = isA ? (i0 + t) : (j0 + (t - 128));
    const int bb  = isA ? b : (b + 4);
    const float* p = feat + ((size_t)bb*CC*HH + (size_t)h)*WW + row;
    float s = 0.f, s2 = 0.f;
    for (int c = 0; c < CC; ++c) {
      float v = p[(size_t)c*HH*WW];
      s += v; s2 = fmaf(v, v, s2);
    }
    float mu  = s * (1.f/CC);
    float var = fmaf(-mu, mu, s2 * (1.f/CC));
    rmean[t] = mu; rrstd[t] = rsqrtf(var + 1e-5f);
  }
  float acc[64];
  #pragma unroll
  for (int q = 0; q < 64; ++q) acc[q] = 0.f;
  const int ty = t >> 4, tx = t & 15;
  const size_t baseA = ((size_t)b*CC*HH + (size_t)h)*WW + i0;
  const size_t baseB = ((size_t)(b+4)*CC*HH + (size_t)h)*WW + j0;
  for (int kc = 0; kc < 2; ++kc) {
    __syncthreads();
    #pragma unroll
    for (int r = 0; r < 8; ++r) {
      int f = r*256 + t;
      int kl = f >> 5, col = (f & 31)*4;
      int ch = kc*64 + kl;
      float lw = lwS[ch], lb = lbS[ch];
      float4 va = *(const float4*)&feat[baseA + (size_t)ch*HH*WW + col];
      float4 rm = *(const float4*)&rmean[col];
      float4 rr = *(const float4*)&rrstd[col];
      va.x = (va.x-rm.x)*rr.x*lw+lb; va.y = (va.y-rm.y)*rr.y*lw+lb;
      va.z = (va.z-rm.z)*rr.z*lw+lb; va.w = (va.w-rm.w)*rr.w*lw+lb;
      *(float4*)&As[kl*128 + col] = va;
      float4 vb = *(const float4*)&feat[baseB + (size_t)ch*HH*WW + col];
      float4 rm2 = *(const float4*)&rmean[128+col];
      float4 rr2 = *(const float4*)&rrstd[128+col];
      vb.x = (vb.x-rm2.x)*rr2.x*lw+lb; vb.y = (vb.y-rm2.y)*rr2.y*lw+lb;
      vb.z = (vb.z-rm2.z)*rr2.z*lw+lb; vb.w = (vb.w-rm2.w)*rr2.w*lw+lb;
      *(float4*)&Bs[kl*128 + col] = vb;
    }
    __syncthreads();
    #pragma unroll 2
    for (int kl = 0; kl < 64; ++kl) {
      float4 a0 = *(const float4*)&As[kl*128 + ty*8];
      float4 a1 = *(const float4*)&As[kl*128 + ty*8 + 4];
      float4 b0 = *(const float4*)&Bs[kl*128 + tx*4];
      float4 b1 = *(const float4*)&Bs[kl*128 + 64 + tx*4];
      float av[8] = {a0.x,a0.y,a0.z,a0.w,a1.x,a1.y,a1.z,a1.w};
      float bv[8] = {b0.x,b0.y,b0.z,b0.w,b1.x,b1.y,b1.z,b1.w};
      #pragma unroll
      for (int rr = 0; rr < 8; ++rr)
        #pragma unroll
        for (int qq = 0; qq < 8; ++qq)
          acc[rr*8+qq] = fmaf(av[rr], bv[qq], acc[rr*8+qq]);
    }
  }
  #pragma unroll
  for (int rr = 0; rr < 8; ++rr) {
    int row = i0 + ty*8 + rr;
    size_t obase = ((size_t)z*256 + row)*256;
    *(float4*)&cv_out[obase + j0 + tx*4] =
        make_float4(acc[rr*8+0],acc[rr*8+1],acc[rr*8+2],acc[rr*8+3]);
    *(float4*)&cv_out[obase + j0 + 64 + tx*4] =
        make_float4(acc[rr*8+4],acc[rr*8+5],acc[rr*8+6],acc[rr*8+7]);
  }
}

// ---------------- downsampled cost volume (h,i strided by 2) ----------------
__global__ __launch_bounds__(256, 2)
void cvd_kernel(const float* __restrict__ feat, const float* __restrict__ lnw,
                const float* __restrict__ lnb, float* __restrict__ cvd_out) {
  extern __shared__ float sm[];
  float* As = sm; float* Bs = sm + 64*128;
  __shared__ __align__(16) float rmean[256];
  __shared__ __align__(16) float rrstd[256];
  __shared__ float lwS[128], lbS[128];
  const int t = threadIdx.x;
  const int z = blockIdx.x, b = z / 40, hd = z % 40, h = 2*hd;
  if (t < 128) { lwS[t] = lnw[t]; lbS[t] = lnb[t]; }
  {
    const int isA = (t < 128);
    const int rowd = isA ? t : (t - 128);
    const int bb = isA ? b : (b + 4);
    const float* p = feat + ((size_t)bb*CC*HH + (size_t)h)*WW + 2*rowd;
    float s = 0.f, s2 = 0.f;
    for (int c = 0; c < CC; ++c) { float v = p[(size_t)c*HH*WW]; s += v; s2 = fmaf(v,v,s2); }
    float mu  = s * (1.f/CC);
    float var = fmaf(-mu, mu, s2 * (1.f/CC));
    rmean[t] = mu; rrstd[t] = rsqrtf(var + 1e-5f);
  }
  float acc[64];
  #pragma unroll
  for (int q = 0; q < 64; ++q) acc[q] = 0.f;
  const int ty = t >> 4, tx = t & 15;
  const size_t baseA = ((size_t)b*CC*HH + (size_t)h)*WW;
  const size_t baseB = ((size_t)(b+4)*CC*HH + (size_t)h)*WW;
  for (int kc = 0; kc < 2; ++kc) {
    __syncthreads();
    #pragma unroll
    for (int r = 0; r < 8; ++r) {
      int f = r*256 + t;
      int kl = f >> 5, col = (f & 31)*4;
      int ch = kc*64 + kl;
      float lw = lwS[ch], lb = lbS[ch];
      const float* pa = &feat[baseA + (size_t)ch*HH*WW + 2*col];
      float4 q0 = *(const float4*)pa;
      float4 q1 = *(const float4*)(pa + 4);
      float4 rm = *(const float4*)&rmean[col];
      float4 rr = *(const float4*)&rrstd[col];
      float4 va = make_float4((q0.x-rm.x)*rr.x*lw+lb, (q0.z-rm.y)*rr.y*lw+lb,
                              (q1.x-rm.z)*rr.z*lw+lb, (q1.z-rm.w)*rr.w*lw+lb);
      *(float4*)&As[kl*128 + col] = va;
      const float* pb = &feat[baseB + (size_t)ch*HH*WW + 2*col];
      float4 s0 = *(const float4*)pb;
      float4 s1 = *(const float4*)(pb + 4);
      float4 rm2 = *(const float4*)&rmean[128+col];
      float4 rr2 = *(const float4*)&rrstd[128+col];
      float4 vb = make_float4((s0.x-rm2.x)*rr2.x*lw+lb, (s0.z-rm2.y)*rr2.y*lw+lb,
                              (s1.x-rm2.z)*rr2.z*lw+lb, (s1.z-rm2.w)*rr2.w*lw+lb);
      *(float4*)&Bs[kl*128 + col] = vb;
    }
    __syncthreads();
    #pragma unroll 2
    for (int kl = 0; kl < 64; ++kl) {
      float4 a0 = *(const float4*)&As[kl*128 + ty*8];
      float4 a1 = *(const float4*)&As[kl*128 + ty*8 + 4];
      float4 b0 = *(const float4*)&Bs[kl*128 + tx*4];
      float4 b1 = *(const float4*)&Bs[kl*128 + 64 + tx*4];
      float av[8] = {a0.x,a0.y,a0.z,a0.w,a1.x,a1.y,a1.z,a1.w};
      float bv[8] = {b0.x,b0.y,b0.z,b0.w,b1.x,b1.y,b1.z,b1.w};
      #pragma unroll
      for (int rr = 0; rr < 8; ++rr)
        #pragma unroll
        for (int qq = 0; qq < 8; ++qq)
          acc[rr*8+qq] = fmaf(av[rr], bv[qq], acc[rr*8+qq]);
    }
  }
  #pragma unroll
  for (int rr = 0; rr < 8; ++rr) {
    int row = ty*8 + rr;
    size_t obase = ((size_t)z*128 + row)*128;
    *(float4*)&cvd_out[obase + tx*4] =
        make_float4(acc[rr*8+0],acc[rr*8+1],acc[rr*8+2],acc[rr*8+3]);
    *(float4*)&cvd_out[obase + 64 + tx*4] =
        make_float4(acc[rr*8+4],acc[rr*8+5],acc[rr*8+6],acc[rr*8+7]);
  }
}

// ---------------- Sinkhorn: 1024 thr/block, wide conflict-free passes --------
// Colsum: wave g<8 owns rows i≡g (mod 8); lane owns cols 4L..4L+3 (one b128/row).
// Rowsum/epilogue: thread (j=t&255, c=t>>8) sums quads bk≡c (mod 4) of row j.
__global__ __launch_bounds__(1024, 4)
void sink_kernel(const float* __restrict__ cvg, float* __restrict__ out) {
  extern __shared__ float pE[];                 // TRI2_TOT floats
  __shared__ int   rowS[256];
  __shared__ __align__(16) float eu[260];
  __shared__ __align__(16) float ev[260];
  __shared__ __align__(16) float buf[8][256];
  __shared__ float vbS[256];
  __shared__ float redbufU[4], redbufV[4], redbuf8[8];
  __shared__ float Msh;
  const int t = threadIdx.x;
  const int z = blockIdx.x;
  const float* cvS = cvg + (size_t)z * 65536;

  if (t < 256) rowS[t] = S_of(t);
  if (t >= 512 && t < 768) eu[t-512] = 1.f;
  if (t == 768) eu[256] = 1.f;

  // ---- pass 1: masked slice max (waves 0-7) ----
  if (t < 512) {
    const int g = t >> 6, lane = t & 63, c0 = 4*(t & 63);
    float mx = 0.f;
    for (int mq = 0; mq < 32; ++mq) {
      int i = 8*mq + g;
      if (lane <= (i >> 2)) {
        float4 v = *(const float4*)&cvS[i*256 + c0];
        if (c0     <= i) mx = fmaxf(mx, v.x);
        if (c0 + 1 <= i) mx = fmaxf(mx, v.y);
        if (c0 + 2 <= i) mx = fmaxf(mx, v.z);
        if (c0 + 3 <= i) mx = fmaxf(mx, v.w);
      }
    }
    #pragma unroll
    for (int mm = 32; mm; mm >>= 1) mx = fmaxf(mx, __shfl_xor(mx, mm, 64));
    if (lane == 0) redbuf8[g] = mx;
  }
  __syncthreads();
  if (t == 0) {
    float m2 = redbuf8[0];
    #pragma unroll
    for (int q = 1; q < 8; ++q) m2 = fmaxf(m2, redbuf8[q]);
    Msh = m2;
  }
  __syncthreads();
  const float M = Msh;
  const float enM = __expf(-M);

  // ---- pass 2: build packed triangle (waves 0-7), b128 writes ----
  if (t < 512) {
    const int g = t >> 6, lane = t & 63, c0 = 4*(t & 63);
    for (int mq = 0; mq < 32; ++mq) {
      int i = 8*mq + g;
      if (lane <= (i >> 2)) {
        int rs = rowS[i];
        float4 v = *(const float4*)&cvS[i*256 + c0];
        float4 e;
        e.x = (c0     <= i) ? __expf(v.x - M) : 0.f;
        e.y = (c0 + 1 <= i) ? __expf(v.y - M) : 0.f;
        e.z = (c0 + 2 <= i) ? __expf(v.z - M) : 0.f;
        e.w = (c0 + 3 <= i) ? __expf(v.w - M) : 0.f;
        *(float4*)&pE[rs + c0] = e;
      }
    }
  }
  __syncthreads();

  const int j = t & 255;
  const int c = t >> 8;
  const int rsR = S_of(j);
  const int nb = (j >> 2) + 1;

  for (int it = 0; it < 8; ++it) {
    // ---- phase A: colsum partials (waves 0-7) + S_eu reduce (waves 8-11) ----
    if (t < 512) {
      const int g = t >> 6, lane = t & 63, c0 = 4*(t & 63);
      float4 a = make_float4(0.f, 0.f, 0.f, 0.f);
      for (int mq = 0; mq < 32; ++mq) {
        int i = 8*mq + g;
        if (lane <= (i >> 2)) {
          int rs = rowS[i];
          float uu = eu[i];
          float4 e = *(const float4*)&pE[rs + c0];
          a.x = fmaf(e.x, uu, a.x);
          a.y = fmaf(e.y, uu, a.y);
          a.z = fmaf(e.z, uu, a.z);
          a.w = fmaf(e.w, uu, a.w);
        }
      }
      *(float4*)&buf[g][c0] = a;
    } else if (t < 768) {
      int tt = t - 512;
      float s = eu[tt];
      #pragma unroll
      for (int mm = 32; mm; mm >>= 1) s += __shfl_xor(s, mm, 64);
      if ((tt & 63) == 0) redbufU[tt >> 6] = s;
    }
    __syncthreads();
    // ---- phase B: ev from column sums; reduce S_ev; pad ev[256] ----
    if (t < 256) {
      float cj = ((buf[0][t] + buf[1][t]) + (buf[2][t] + buf[3][t]))
               + ((buf[4][t] + buf[5][t]) + (buf[6][t] + buf[7][t]))
               + enM * eu[256];
      float evt = NU_C / cj;
      ev[t] = evt;
      float s = evt;
      #pragma unroll
      for (int mm = 32; mm; mm >>= 1) s += __shfl_xor(s, mm, 64);
      if ((t & 63) == 0) redbufV[t >> 6] = s;
    } else if (t == 960) {
      float S = ((redbufU[0] + redbufU[1]) + (redbufU[2] + redbufU[3])) + eu[256];
      ev[256] = 0.5f / (enM * S);
    }
    __syncthreads();
    // ---- phase C: rowsum partials (all 16 waves) ----
    {
      float r0 = 0.f, r1 = 0.f, r2 = 0.f, r3 = 0.f;
      for (int bk = c; bk < nb; bk += 4) {
        float4 e4  = *(const float4*)&pE[rsR + 4*bk];
        float4 ev4 = *(const float4*)&ev[4*bk];
        r0 = fmaf(e4.x, ev4.x, r0);
        r1 = fmaf(e4.y, ev4.y, r1);
        r2 = fmaf(e4.z, ev4.z, r2);
        r3 = fmaf(e4.w, ev4.w, r3);
      }
      buf[c][j] = (r0 + r1) + (r2 + r3);
    }
    __syncthreads();
    // ---- phase D: eu from row sums; pad eu[256] ----
    if (t < 256) {
      float ri = ((buf[0][t] + buf[1][t]) + (buf[2][t] + buf[3][t]))
               + enM * ev[256];
      eu[t] = MU_C / ri;
    } else if (t == 960) {
      float S = ((redbufV[0] + redbufV[1]) + (redbufV[2] + redbufV[3])) + ev[256];
      eu[256] = 0.5f / (enM * S);
    }
    __syncthreads();
  }

  // ---- epilogue: occ / first-max argmax / conf / corr ----
  {
    float occ = 0.f, vmax = -1.f;
    int jm = 1 << 30;
    for (int bk = c; bk < nb; bk += 4) {
      float4 e4  = *(const float4*)&pE[rsR + 4*bk];
      float4 ev4 = *(const float4*)&ev[4*bk];
      float p0 = e4.x*ev4.x, p1 = e4.y*ev4.y, p2 = e4.z*ev4.z, p3 = e4.w*ev4.w;
      occ += (p0 + p1) + (p2 + p3);
      if (p0 > vmax) { vmax = p0; jm = 4*bk;   }
      if (p1 > vmax) { vmax = p1; jm = 4*bk+1; }
      if (p2 > vmax) { vmax = p2; jm = 4*bk+2; }
      if (p3 > vmax) { vmax = p3; jm = 4*bk+3; }
    }
    buf[c][j] = occ;                        // phase A': occ partials
    __syncthreads();
    if (t < 256) {
      float occT = ((buf[0][t] + buf[1][t]) + (buf[2][t] + buf[3][t]));
      out[OCC_OFF + z*256 + t] = occT * eu[t] * 512.f;
    }
    __syncthreads();
    buf[c][j] = vmax;                       // phase B': vmax partials
    __syncthreads();
    if (t < 256)
      vbS[t] = fmaxf(fmaxf(buf[0][t], buf[1][t]), fmaxf(buf[2][t], buf[3][t]));
    __syncthreads();
    ((int*)buf)[c*256 + j] = (vmax == vbS[j]) ? jm : (1 << 30);  // phase C'
    __syncthreads();
    if (t < 256) {
      const int* bi = (const int*)buf;
      int jb = min(min(bi[t], bi[256 + t]), min(bi[512 + t], bi[768 + t]));
      const int rsT = S_of(t);
      const float sc = eu[t] * 512.f;
      float conf = 0.f, corr = 0.f;
      #pragma unroll
      for (int d = 0; d < 5; ++d) {
        int jp = jb + d - 2;
        float wgt = 0.f;
        if (jp >= 0 && jp <= t) wgt = pE[rsT + jp] * ev[jp] * sc;
        conf += wgt;
        corr = fmaf(wgt, (float)jp, corr);
      }
      corr = (corr + 1e-4f) / (conf + 1e-4f);
      out[DISP_OFF + z*256 + t] = (float)t - corr;
      out[CONF_OFF + z*256 + t] = conf;
    }
  }
}

extern "C" void kernel_launch(void* const* d_in, const int* in_sizes, int n_in,
                              void* d_out, int out_size, void* d_ws, size_t ws_size,
                              hipStream_t stream) {
  (void)in_sizes; (void)n_in; (void)out_size; (void)d_ws; (void)ws_size;
  const float* feat = (const float*)d_in[0];
  const float* lnw  = (const float*)d_in[1];
  const float* lnb  = (const float*)d_in[2];
  float* out = (float*)d_out;

  (void)hipFuncSetAttribute((const void*)cv_kernel,
                            hipFuncAttributeMaxDynamicSharedMemorySize, 65536);
  (void)hipFuncSetAttribute((const void*)cvd_kernel,
                            hipFuncAttributeMaxDynamicSharedMemorySize, 65536);
  (void)hipFuncSetAttribute((const void*)sink_kernel,
                            hipFuncAttributeMaxDynamicSharedMemorySize, TRI2_TOT*4);

  cv_kernel<<<dim3(2, 2, NSL), 256, 65536, stream>>>(feat, lnw, lnb, out + CV_OFF);
  sink_kernel<<<dim3(NSL), 1024, TRI2_TOT*4, stream>>>(out + CV_OFF, out);
  cvd_kernel<<<dim3(160), 256, 65536, stream>>>(feat, lnw, lnb, out + CVD_OFF);
}

// Round 5
// 411.132 us; speedup vs baseline: 2.2372x; 1.0060x over previous
//
#include <hip/hip_runtime.h>

#define CC 128
#define HH 80
#define WW 256
#define NSL 320                 // 4*80 slices
#define TRI2_TOT 36864          // quad-uniform staggered triangle, floats (144 KB)
#define DISP_OFF 0
#define CONF_OFF 81920
#define OCC_OFF  163840
#define CV_OFF   245760
#define CVD_OFF  21217280
#define NU_C (1.0f/512.0f)
#define MU_C (1.0f/512.0f)

// Quad m (rows 4m..4m+3) all have padded length ell(m) = 4 + 32*((m+7)>>3).
// Row start S(i) = Q(m) + (i&3)*ell(m), Q(m) = 16m + 128*G(m),
// G(m) = 4q(q-1) + r*q with q=(m+7)>>3, r=(m+7)&7.
// Properties: S(i) ≡ 4i (mod 32) -> b128 row reads conflict-free; S(i) ≡ 0 (mod 4).
__device__ __forceinline__ int ell_of(int m) { return 4 + (((m + 7) >> 3) << 5); }
__device__ __forceinline__ int S_of(int i) {
  int m = i >> 2;
  int q = (m + 7) >> 3, r = (m + 7) & 7;
  int Q = 16*m + ((q*(q-1)) << 9) + ((r*q) << 7);
  return Q + (i & 3) * ell_of(m);
}

// ---------------- cost-volume GEMM with fused LayerNorm ----------------
__global__ __launch_bounds__(256, 2)
void cv_kernel(const float* __restrict__ feat, const float* __restrict__ lnw,
               const float* __restrict__ lnb, float* __restrict__ cv_out) {
  extern __shared__ float sm[];
  float* As = sm;              // [64][128] k-major
  float* Bs = sm + 64*128;
  __shared__ __align__(16) float rmean[256];
  __shared__ __align__(16) float rrstd[256];
  __shared__ float lwS[128], lbS[128];
  const int t = threadIdx.x;
  const int z = blockIdx.z, b = z / HH, h = z % HH;
  const int i0 = blockIdx.y * 128, j0 = blockIdx.x * 128;
  if (t < 128) { lwS[t] = lnw[t]; lbS[t] = lnb[t]; }
  {
    const int isA = (t < 128);
    const int row = isA ? (i0 + t) : (j0 + (t - 128));
    const int bb  = isA ? b : (b + 4);
    const float* p = feat + ((size_t)bb*CC*HH + (size_t)h)*WW + row;
    float s = 0.f, s2 = 0.f;
    for (int c = 0; c < CC; ++c) {
      float v = p[(size_t)c*HH*WW];
      s += v; s2 = fmaf(v, v, s2);
    }
    float mu  = s * (1.f/CC);
    float var = fmaf(-mu, mu, s2 * (1.f/CC));
    rmean[t] = mu; rrstd[t] = rsqrtf(var + 1e-5f);
  }
  float acc[64];
  #pragma unroll
  for (int q = 0; q < 64; ++q) acc[q] = 0.f;
  const int ty = t >> 4, tx = t & 15;
  const size_t baseA = ((size_t)b*CC*HH + (size_t)h)*WW + i0;
  const size_t baseB = ((size_t)(b+4)*CC*HH + (size_t)h)*WW + j0;
  for (int kc = 0; kc < 2; ++kc) {
    __syncthreads();
    #pragma unroll
    for (int r = 0; r < 8; ++r) {
      int f = r*256 + t;
      int kl = f >> 5, col = (f & 31)*4;
      int ch = kc*64 + kl;
      float lw = lwS[ch], lb = lbS[ch];
      float4 va = *(const float4*)&feat[baseA + (size_t)ch*HH*WW + col];
      float4 rm = *(const float4*)&rmean[col];
      float4 rr = *(const float4*)&rrstd[col];
      va.x = (va.x-rm.x)*rr.x*lw+lb; va.y = (va.y-rm.y)*rr.y*lw+lb;
      va.z = (va.z-rm.z)*rr.z*lw+lb; va.w = (va.w-rm.w)*rr.w*lw+lb;
      *(float4*)&As[kl*128 + col] = va;
      float4 vb = *(const float4*)&feat[baseB + (size_t)ch*HH*WW + col];
      float4 rm2 = *(const float4*)&rmean[128+col];
      float4 rr2 = *(const float4*)&rrstd[128+col];
      vb.x = (vb.x-rm2.x)*rr2.x*lw+lb; vb.y = (vb.y-rm2.y)*rr2.y*lw+lb;
      vb.z = (vb.z-rm2.z)*rr2.z*lw+lb; vb.w = (vb.w-rm2.w)*rr2.w*lw+lb;
      *(float4*)&Bs[kl*128 + col] = vb;
    }
    __syncthreads();
    #pragma unroll 2
    for (int kl = 0; kl < 64; ++kl) {
      float4 a0 = *(const float4*)&As[kl*128 + ty*8];
      float4 a1 = *(const float4*)&As[kl*128 + ty*8 + 4];
      float4 b0 = *(const float4*)&Bs[kl*128 + tx*4];
      float4 b1 = *(const float4*)&Bs[kl*128 + 64 + tx*4];
      float av[8] = {a0.x,a0.y,a0.z,a0.w,a1.x,a1.y,a1.z,a1.w};
      float bv[8] = {b0.x,b0.y,b0.z,b0.w,b1.x,b1.y,b1.z,b1.w};
      #pragma unroll
      for (int rr = 0; rr < 8; ++rr)
        #pragma unroll
        for (int qq = 0; qq < 8; ++qq)
          acc[rr*8+qq] = fmaf(av[rr], bv[qq], acc[rr*8+qq]);
    }
  }
  #pragma unroll
  for (int rr = 0; rr < 8; ++rr) {
    int row = i0 + ty*8 + rr;
    size_t obase = ((size_t)z*256 + row)*256;
    *(float4*)&cv_out[obase + j0 + tx*4] =
        make_float4(acc[rr*8+0],acc[rr*8+1],acc[rr*8+2],acc[rr*8+3]);
    *(float4*)&cv_out[obase + j0 + 64 + tx*4] =
        make_float4(acc[rr*8+4],acc[rr*8+5],acc[rr*8+6],acc[rr*8+7]);
  }
}

// ---------------- downsampled cost volume (h,i strided by 2) ----------------
__global__ __launch_bounds__(256, 2)
void cvd_kernel(const float* __restrict__ feat, const float* __restrict__ lnw,
                const float* __restrict__ lnb, float* __restrict__ cvd_out) {
  extern __shared__ float sm[];
  float* As = sm; float* Bs = sm + 64*128;
  __shared__ __align__(16) float rmean[256];
  __shared__ __align__(16) float rrstd[256];
  __shared__ float lwS[128], lbS[128];
  const int t = threadIdx.x;
  const int z = blockIdx.x, b = z / 40, hd = z % 40, h = 2*hd;
  if (t < 128) { lwS[t] = lnw[t]; lbS[t] = lnb[t]; }
  {
    const int isA = (t < 128);
    const int rowd = isA ? t : (t - 128);
    const int bb = isA ? b : (b + 4);
    const float* p = feat + ((size_t)bb*CC*HH + (size_t)h)*WW + 2*rowd;
    float s = 0.f, s2 = 0.f;
    for (int c = 0; c < CC; ++c) { float v = p[(size_t)c*HH*WW]; s += v; s2 = fmaf(v,v,s2); }
    float mu  = s * (1.f/CC);
    float var = fmaf(-mu, mu, s2 * (1.f/CC));
    rmean[t] = mu; rrstd[t] = rsqrtf(var + 1e-5f);
  }
  float acc[64];
  #pragma unroll
  for (int q = 0; q < 64; ++q) acc[q] = 0.f;
  const int ty = t >> 4, tx = t & 15;
  const size_t baseA = ((size_t)b*CC*HH + (size_t)h)*WW;
  const size_t baseB = ((size_t)(b+4)*CC*HH + (size_t)h)*WW;
  for (int kc = 0; kc < 2; ++kc) {
    __syncthreads();
    #pragma unroll
    for (int r = 0; r < 8; ++r) {
      int f = r*256 + t;
      int kl = f >> 5, col = (f & 31)*4;
      int ch = kc*64 + kl;
      float lw = lwS[ch], lb = lbS[ch];
      const float* pa = &feat[baseA + (size_t)ch*HH*WW + 2*col];
      float4 q0 = *(const float4*)pa;
      float4 q1 = *(const float4*)(pa + 4);
      float4 rm = *(const float4*)&rmean[col];
      float4 rr = *(const float4*)&rrstd[col];
      float4 va = make_float4((q0.x-rm.x)*rr.x*lw+lb, (q0.z-rm.y)*rr.y*lw+lb,
                              (q1.x-rm.z)*rr.z*lw+lb, (q1.z-rm.w)*rr.w*lw+lb);
      *(float4*)&As[kl*128 + col] = va;
      const float* pb = &feat[baseB + (size_t)ch*HH*WW + 2*col];
      float4 s0 = *(const float4*)pb;
      float4 s1 = *(const float4*)(pb + 4);
      float4 rm2 = *(const float4*)&rmean[128+col];
      float4 rr2 = *(const float4*)&rrstd[128+col];
      float4 vb = make_float4((s0.x-rm2.x)*rr2.x*lw+lb, (s0.z-rm2.y)*rr2.y*lw+lb,
                              (s1.x-rm2.z)*rr2.z*lw+lb, (s1.z-rm2.w)*rr2.w*lw+lb);
      *(float4*)&Bs[kl*128 + col] = vb;
    }
    __syncthreads();
    #pragma unroll 2
    for (int kl = 0; kl < 64; ++kl) {
      float4 a0 = *(const float4*)&As[kl*128 + ty*8];
      float4 a1 = *(const float4*)&As[kl*128 + ty*8 + 4];
      float4 b0 = *(const float4*)&Bs[kl*128 + tx*4];
      float4 b1 = *(const float4*)&Bs[kl*128 + 64 + tx*4];
      float av[8] = {a0.x,a0.y,a0.z,a0.w,a1.x,a1.y,a1.z,a1.w};
      float bv[8] = {b0.x,b0.y,b0.z,b0.w,b1.x,b1.y,b1.z,b1.w};
      #pragma unroll
      for (int rr = 0; rr < 8; ++rr)
        #pragma unroll
        for (int qq = 0; qq < 8; ++qq)
          acc[rr*8+qq] = fmaf(av[rr], bv[qq], acc[rr*8+qq]);
    }
  }
  #pragma unroll
  for (int rr = 0; rr < 8; ++rr) {
    int row = ty*8 + rr;
    size_t obase = ((size_t)z*128 + row)*128;
    *(float4*)&cvd_out[obase + tx*4] =
        make_float4(acc[rr*8+0],acc[rr*8+1],acc[rr*8+2],acc[rr*8+3]);
    *(float4*)&cvd_out[obase + 64 + tx*4] =
        make_float4(acc[rr*8+4],acc[rr*8+5],acc[rr*8+6],acc[rr*8+7]);
  }
}

// ---------------- Sinkhorn: row stripes cached in VGPRs ----------------------
// E never changes across iterations. Thread (j=t&255, c=t>>8) caches its
// rowsum stripe (quads bk≡c mod 4 of row j, ≤16 float4) in registers after
// build; rowsum + epilogue then never touch pE in LDS. Colsum (waves 0-7,
// rows i≡g mod 8, lane=column-quad) is the only remaining triangle stream.
__global__ __launch_bounds__(1024, 4)
void sink_kernel(const float* __restrict__ cvg, float* __restrict__ out) {
  extern __shared__ float pE[];                 // TRI2_TOT floats
  __shared__ __align__(16) float eu[260];
  __shared__ __align__(16) float ev[260];
  __shared__ __align__(16) float buf[8][256];
  __shared__ float vbS[256];
  __shared__ float redbufU[4], redbufV[4], redbuf8[8];
  __shared__ float Msh;
  const int t = threadIdx.x;
  const int z = blockIdx.x;
  const float* cvS = cvg + (size_t)z * 65536;

  if (t >= 512 && t < 768) eu[t-512] = 1.f;
  if (t == 768) eu[256] = 1.f;

  // ---- pass 1: masked slice max (waves 0-7) ----
  if (t < 512) {
    const int g = t >> 6, lane = t & 63, c0 = 4*(t & 63);
    float mx = 0.f;
    for (int mq = 0; mq < 32; ++mq) {
      int i = 8*mq + g;
      if (lane <= (i >> 2)) {
        float4 v = *(const float4*)&cvS[i*256 + c0];
        if (c0     <= i) mx = fmaxf(mx, v.x);
        if (c0 + 1 <= i) mx = fmaxf(mx, v.y);
        if (c0 + 2 <= i) mx = fmaxf(mx, v.z);
        if (c0 + 3 <= i) mx = fmaxf(mx, v.w);
      }
    }
    #pragma unroll
    for (int mm = 32; mm; mm >>= 1) mx = fmaxf(mx, __shfl_xor(mx, mm, 64));
    if (lane == 0) redbuf8[g] = mx;
  }
  __syncthreads();
  if (t == 0) {
    float m2 = redbuf8[0];
    #pragma unroll
    for (int q = 1; q < 8; ++q) m2 = fmaxf(m2, redbuf8[q]);
    Msh = m2;
  }
  __syncthreads();
  const float M = Msh;
  const float enM = __expf(-M);

  // ---- pass 2: build packed triangle (waves 0-7), b128 writes ----
  if (t < 512) {
    const int g = t >> 6, lane = t & 63, c0 = 4*(t & 63);
    for (int mq = 0; mq < 32; ++mq) {
      int i = 8*mq + g;
      if (lane <= (i >> 2)) {
        int rs = S_of(i);
        float4 v = *(const float4*)&cvS[i*256 + c0];
        float4 e;
        e.x = (c0     <= i) ? __expf(v.x - M) : 0.f;
        e.y = (c0 + 1 <= i) ? __expf(v.y - M) : 0.f;
        e.z = (c0 + 2 <= i) ? __expf(v.z - M) : 0.f;
        e.w = (c0 + 3 <= i) ? __expf(v.w - M) : 0.f;
        *(float4*)&pE[rs + c0] = e;
      }
    }
  }
  __syncthreads();

  const int j = t & 255;
  const int c = t >> 8;
  const int rsR = S_of(j);
  const int nb = (j >> 2) + 1;

  // ---- cache this thread's rowsum stripe in registers (zero-fill OOB) ----
  float4 eR[16];
  #pragma unroll
  for (int r = 0; r < 16; ++r) {
    int bk = c + 4*r;
    eR[r] = (bk < nb) ? *(const float4*)&pE[rsR + 4*bk]
                      : make_float4(0.f, 0.f, 0.f, 0.f);
  }

  for (int it = 0; it < 8; ++it) {
    // ---- phase A: colsum partials (waves 0-7) + S_eu reduce (waves 8-11) ---
    if (t < 512) {
      const int g = t >> 6, lane = t & 63, c0 = 4*(t & 63);
      float4 a = make_float4(0.f, 0.f, 0.f, 0.f);
      #pragma unroll 2
      for (int mq = 0; mq < 32; mq += 2) {
        int i0 = 8*mq + g, i1 = i0 + 8;
        float u0 = eu[i0], u1 = eu[i1];
        int rs0 = S_of(i0), rs1 = S_of(i1);
        if (lane <= (i0 >> 2)) {
          float4 e = *(const float4*)&pE[rs0 + c0];
          a.x = fmaf(e.x, u0, a.x); a.y = fmaf(e.y, u0, a.y);
          a.z = fmaf(e.z, u0, a.z); a.w = fmaf(e.w, u0, a.w);
        }
        if (lane <= (i1 >> 2)) {
          float4 e = *(const float4*)&pE[rs1 + c0];
          a.x = fmaf(e.x, u1, a.x); a.y = fmaf(e.y, u1, a.y);
          a.z = fmaf(e.z, u1, a.z); a.w = fmaf(e.w, u1, a.w);
        }
      }
      *(float4*)&buf[g][c0] = a;
    } else if (t < 768) {
      int tt = t - 512;
      float s = eu[tt];
      #pragma unroll
      for (int mm = 32; mm; mm >>= 1) s += __shfl_xor(s, mm, 64);
      if ((tt & 63) == 0) redbufU[tt >> 6] = s;
    }
    __syncthreads();
    // ---- phase B: ev from column sums; reduce S_ev; pad ev[256] ----
    if (t < 256) {
      float cj = ((buf[0][t] + buf[1][t]) + (buf[2][t] + buf[3][t]))
               + ((buf[4][t] + buf[5][t]) + (buf[6][t] + buf[7][t]))
               + enM * eu[256];
      float evt = NU_C / cj;
      ev[t] = evt;
      float s = evt;
      #pragma unroll
      for (int mm = 32; mm; mm >>= 1) s += __shfl_xor(s, mm, 64);
      if ((t & 63) == 0) redbufV[t >> 6] = s;
    } else if (t == 960) {
      float S = ((redbufU[0] + redbufU[1]) + (redbufU[2] + redbufU[3])) + eu[256];
      ev[256] = 0.5f / (enM * S);
    }
    __syncthreads();
    // ---- phase C: rowsum partials from registers (all 16 waves) ----
    {
      float r0 = 0.f, r1 = 0.f, r2 = 0.f, r3 = 0.f;
      #pragma unroll
      for (int r = 0; r < 16; ++r) {
        int bk = c + 4*r;
        float4 ev4 = *(const float4*)&ev[4*bk & 1023];
        r0 = fmaf(eR[r].x, ev4.x, r0);
        r1 = fmaf(eR[r].y, ev4.y, r1);
        r2 = fmaf(eR[r].z, ev4.z, r2);
        r3 = fmaf(eR[r].w, ev4.w, r3);
      }
      buf[c][j] = (r0 + r1) + (r2 + r3);
    }
    __syncthreads();
    // ---- phase D: eu from row sums; pad eu[256] ----
    if (t < 256) {
      float ri = ((buf[0][t] + buf[1][t]) + (buf[2][t] + buf[3][t]))
               + enM * ev[256];
      eu[t] = MU_C / ri;
    } else if (t == 960) {
      float S = ((redbufV[0] + redbufV[1]) + (redbufV[2] + redbufV[3])) + ev[256];
      eu[256] = 0.5f / (enM * S);
    }
    __syncthreads();
  }

  // ---- epilogue: occ / first-max argmax / conf / corr (from registers) ----
  {
    float occ = 0.f, vmax = -1.f;
    int jm = 1 << 30;
    #pragma unroll
    for (int r = 0; r < 16; ++r) {
      int bk = c + 4*r;
      float4 ev4 = *(const float4*)&ev[4*bk & 1023];
      float p0 = eR[r].x*ev4.x, p1 = eR[r].y*ev4.y,
            p2 = eR[r].z*ev4.z, p3 = eR[r].w*ev4.w;
      occ += (p0 + p1) + (p2 + p3);
      if (p0 > vmax) { vmax = p0; jm = 4*bk;   }
      if (p1 > vmax) { vmax = p1; jm = 4*bk+1; }
      if (p2 > vmax) { vmax = p2; jm = 4*bk+2; }
      if (p3 > vmax) { vmax = p3; jm = 4*bk+3; }
    }
    buf[c][j] = occ;                        // phase A': occ partials
    __syncthreads();
    if (t < 256) {
      float occT = ((buf[0][t] + buf[1][t]) + (buf[2][t] + buf[3][t]));
      out[OCC_OFF + z*256 + t] = occT * eu[t] * 512.f;
    }
    __syncthreads();
    buf[c][j] = vmax;                       // phase B': vmax partials
    __syncthreads();
    if (t < 256)
      vbS[t] = fmaxf(fmaxf(buf[0][t], buf[1][t]), fmaxf(buf[2][t], buf[3][t]));
    __syncthreads();
    ((int*)buf)[c*256 + j] = (vmax == vbS[j]) ? jm : (1 << 30);  // phase C'
    __syncthreads();
    if (t < 256) {
      const int* bi = (const int*)buf;
      int jb = min(min(bi[t], bi[256 + t]), min(bi[512 + t], bi[768 + t]));
      const int rsT = S_of(t);
      const float sc = eu[t] * 512.f;
      float conf = 0.f, corr = 0.f;
      #pragma unroll
      for (int d = 0; d < 5; ++d) {
        int jp = jb + d - 2;
        float wgt = 0.f;
        if (jp >= 0 && jp <= t) wgt = pE[rsT + jp] * ev[jp] * sc;
        conf += wgt;
        corr = fmaf(wgt, (float)jp, corr);
      }
      corr = (corr + 1e-4f) / (conf + 1e-4f);
      out[DISP_OFF + z*256 + t] = (float)t - corr;
      out[CONF_OFF + z*256 + t] = conf;
    }
  }
}

extern "C" void kernel_launch(void* const* d_in, const int* in_sizes, int n_in,
                              void* d_out, int out_size, void* d_ws, size_t ws_size,
                              hipStream_t stream) {
  (void)in_sizes; (void)n_in; (void)out_size; (void)d_ws; (void)ws_size;
  const float* feat = (const float*)d_in[0];
  const float* lnw  = (const float*)d_in[1];
  const float* lnb  = (const float*)d_in[2];
  float* out = (float*)d_out;

  (void)hipFuncSetAttribute((const void*)cv_kernel,
                            hipFuncAttributeMaxDynamicSharedMemorySize, 65536);
  (void)hipFuncSetAttribute((const void*)cvd_kernel,
                            hipFuncAttributeMaxDynamicSharedMemorySize, 65536);
  (void)hipFuncSetAttribute((const void*)sink_kernel,
                            hipFuncAttributeMaxDynamicSharedMemorySize, TRI2_TOT*4);

  cv_kernel<<<dim3(2, 2, NSL), 256, 65536, stream>>>(feat, lnw, lnb, out + CV_OFF);
  sink_kernel<<<dim3(NSL), 1024, TRI2_TOT*4, stream>>>(out + CV_OFF, out);
  cvd_kernel<<<dim3(160), 256, 65536, stream>>>(feat, lnw, lnb, out + CVD_OFF);
}

// Round 6
// 407.878 us; speedup vs baseline: 2.2551x; 1.0080x over previous
//
#include <hip/hip_runtime.h>

#define CC 128
#define HH 80
#define WW 256
#define NSL 320                 // 4*80 slices
#define TRI2_TOT 36864          // quad-uniform staggered triangle, floats (144 KB)
#define DISP_OFF 0
#define CONF_OFF 81920
#define OCC_OFF  163840
#define CV_OFF   245760
#define CVD_OFF  21217280
#define NU_C (1.0f/512.0f)
#define MU_C (1.0f/512.0f)

// Quad m (rows 4m..4m+3) all have padded length ell(m) = 4 + 32*((m+7)>>3).
// Row start S(i) = Q(m) + (i&3)*ell(m), Q(m) = 16m + 128*G(m),
// G(m) = 4q(q-1) + r*q with q=(m+7)>>3, r=(m+7)&7.
// Properties: S(i) ≡ 4i (mod 32) -> b128 row reads conflict-free; S(i) ≡ 0 (mod 4).
__device__ __forceinline__ int ell_of(int m) { return 4 + (((m + 7) >> 3) << 5); }
__device__ __forceinline__ int S_of(int i) {
  int m = i >> 2;
  int q = (m + 7) >> 3, r = (m + 7) & 7;
  int Q = 16*m + ((q*(q-1)) << 9) + ((r*q) << 7);
  return Q + (i & 3) * ell_of(m);
}

// ---------------- cost-volume GEMM with fused LayerNorm ----------------
__global__ __launch_bounds__(256, 2)
void cv_kernel(const float* __restrict__ feat, const float* __restrict__ lnw,
               const float* __restrict__ lnb, float* __restrict__ cv_out) {
  extern __shared__ float sm[];
  float* As = sm;              // [64][128] k-major
  float* Bs = sm + 64*128;
  __shared__ __align__(16) float rmean[256];
  __shared__ __align__(16) float rrstd[256];
  __shared__ float lwS[128], lbS[128];
  const int t = threadIdx.x;
  const int z = blockIdx.z, b = z / HH, h = z % HH;
  const int i0 = blockIdx.y * 128, j0 = blockIdx.x * 128;
  if (t < 128) { lwS[t] = lnw[t]; lbS[t] = lnb[t]; }
  {
    const int isA = (t < 128);
    const int row = isA ? (i0 + t) : (j0 + (t - 128));
    const int bb  = isA ? b : (b + 4);
    const float* p = feat + ((size_t)bb*CC*HH + (size_t)h)*WW + row;
    float s = 0.f, s2 = 0.f;
    for (int c = 0; c < CC; ++c) {
      float v = p[(size_t)c*HH*WW];
      s += v; s2 = fmaf(v, v, s2);
    }
    float mu  = s * (1.f/CC);
    float var = fmaf(-mu, mu, s2 * (1.f/CC));
    rmean[t] = mu; rrstd[t] = rsqrtf(var + 1e-5f);
  }
  float acc[64];
  #pragma unroll
  for (int q = 0; q < 64; ++q) acc[q] = 0.f;
  const int ty = t >> 4, tx = t & 15;
  const size_t baseA = ((size_t)b*CC*HH + (size_t)h)*WW + i0;
  const size_t baseB = ((size_t)(b+4)*CC*HH + (size_t)h)*WW + j0;
  for (int kc = 0; kc < 2; ++kc) {
    __syncthreads();
    #pragma unroll
    for (int r = 0; r < 8; ++r) {
      int f = r*256 + t;
      int kl = f >> 5, col = (f & 31)*4;
      int ch = kc*64 + kl;
      float lw = lwS[ch], lb = lbS[ch];
      float4 va = *(const float4*)&feat[baseA + (size_t)ch*HH*WW + col];
      float4 rm = *(const float4*)&rmean[col];
      float4 rr = *(const float4*)&rrstd[col];
      va.x = (va.x-rm.x)*rr.x*lw+lb; va.y = (va.y-rm.y)*rr.y*lw+lb;
      va.z = (va.z-rm.z)*rr.z*lw+lb; va.w = (va.w-rm.w)*rr.w*lw+lb;
      *(float4*)&As[kl*128 + col] = va;
      float4 vb = *(const float4*)&feat[baseB + (size_t)ch*HH*WW + col];
      float4 rm2 = *(const float4*)&rmean[128+col];
      float4 rr2 = *(const float4*)&rrstd[128+col];
      vb.x = (vb.x-rm2.x)*rr2.x*lw+lb; vb.y = (vb.y-rm2.y)*rr2.y*lw+lb;
      vb.z = (vb.z-rm2.z)*rr2.z*lw+lb; vb.w = (vb.w-rm2.w)*rr2.w*lw+lb;
      *(float4*)&Bs[kl*128 + col] = vb;
    }
    __syncthreads();
    #pragma unroll 2
    for (int kl = 0; kl < 64; ++kl) {
      float4 a0 = *(const float4*)&As[kl*128 + ty*8];
      float4 a1 = *(const float4*)&As[kl*128 + ty*8 + 4];
      float4 b0 = *(const float4*)&Bs[kl*128 + tx*4];
      float4 b1 = *(const float4*)&Bs[kl*128 + 64 + tx*4];
      float av[8] = {a0.x,a0.y,a0.z,a0.w,a1.x,a1.y,a1.z,a1.w};
      float bv[8] = {b0.x,b0.y,b0.z,b0.w,b1.x,b1.y,b1.z,b1.w};
      #pragma unroll
      for (int rr = 0; rr < 8; ++rr)
        #pragma unroll
        for (int qq = 0; qq < 8; ++qq)
          acc[rr*8+qq] = fmaf(av[rr], bv[qq], acc[rr*8+qq]);
    }
  }
  #pragma unroll
  for (int rr = 0; rr < 8; ++rr) {
    int row = i0 + ty*8 + rr;
    size_t obase = ((size_t)z*256 + row)*256;
    *(float4*)&cv_out[obase + j0 + tx*4] =
        make_float4(acc[rr*8+0],acc[rr*8+1],acc[rr*8+2],acc[rr*8+3]);
    *(float4*)&cv_out[obase + j0 + 64 + tx*4] =
        make_float4(acc[rr*8+4],acc[rr*8+5],acc[rr*8+6],acc[rr*8+7]);
  }
}

// ---------------- downsampled cost volume (h,i strided by 2) ----------------
__global__ __launch_bounds__(256, 2)
void cvd_kernel(const float* __restrict__ feat, const float* __restrict__ lnw,
                const float* __restrict__ lnb, float* __restrict__ cvd_out) {
  extern __shared__ float sm[];
  float* As = sm; float* Bs = sm + 64*128;
  __shared__ __align__(16) float rmean[256];
  __shared__ __align__(16) float rrstd[256];
  __shared__ float lwS[128], lbS[128];
  const int t = threadIdx.x;
  const int z = blockIdx.x, b = z / 40, hd = z % 40, h = 2*hd;
  if (t < 128) { lwS[t] = lnw[t]; lbS[t] = lnb[t]; }
  {
    const int isA = (t < 128);
    const int rowd = isA ? t : (t - 128);
    const int bb = isA ? b : (b + 4);
    const float* p = feat + ((size_t)bb*CC*HH + (size_t)h)*WW + 2*rowd;
    float s = 0.f, s2 = 0.f;
    for (int c = 0; c < CC; ++c) { float v = p[(size_t)c*HH*WW]; s += v; s2 = fmaf(v,v,s2); }
    float mu  = s * (1.f/CC);
    float var = fmaf(-mu, mu, s2 * (1.f/CC));
    rmean[t] = mu; rrstd[t] = rsqrtf(var + 1e-5f);
  }
  float acc[64];
  #pragma unroll
  for (int q = 0; q < 64; ++q) acc[q] = 0.f;
  const int ty = t >> 4, tx = t & 15;
  const size_t baseA = ((size_t)b*CC*HH + (size_t)h)*WW;
  const size_t baseB = ((size_t)(b+4)*CC*HH + (size_t)h)*WW;
  for (int kc = 0; kc < 2; ++kc) {
    __syncthreads();
    #pragma unroll
    for (int r = 0; r < 8; ++r) {
      int f = r*256 + t;
      int kl = f >> 5, col = (f & 31)*4;
      int ch = kc*64 + kl;
      float lw = lwS[ch], lb = lbS[ch];
      const float* pa = &feat[baseA + (size_t)ch*HH*WW + 2*col];
      float4 q0 = *(const float4*)pa;
      float4 q1 = *(const float4*)(pa + 4);
      float4 rm = *(const float4*)&rmean[col];
      float4 rr = *(const float4*)&rrstd[col];
      float4 va = make_float4((q0.x-rm.x)*rr.x*lw+lb, (q0.z-rm.y)*rr.y*lw+lb,
                              (q1.x-rm.z)*rr.z*lw+lb, (q1.z-rm.w)*rr.w*lw+lb);
      *(float4*)&As[kl*128 + col] = va;
      const float* pb = &feat[baseB + (size_t)ch*HH*WW + 2*col];
      float4 s0 = *(const float4*)pb;
      float4 s1 = *(const float4*)(pb + 4);
      float4 rm2 = *(const float4*)&rmean[128+col];
      float4 rr2 = *(const float4*)&rrstd[128+col];
      float4 vb = make_float4((s0.x-rm2.x)*rr2.x*lw+lb, (s0.z-rm2.y)*rr2.y*lw+lb,
                              (s1.x-rm2.z)*rr2.z*lw+lb, (s1.z-rm2.w)*rr2.w*lw+lb);
      *(float4*)&Bs[kl*128 + col] = vb;
    }
    __syncthreads();
    #pragma unroll 2
    for (int kl = 0; kl < 64; ++kl) {
      float4 a0 = *(const float4*)&As[kl*128 + ty*8];
      float4 a1 = *(const float4*)&As[kl*128 + ty*8 + 4];
      float4 b0 = *(const float4*)&Bs[kl*128 + tx*4];
      float4 b1 = *(const float4*)&Bs[kl*128 + 64 + tx*4];
      float av[8] = {a0.x,a0.y,a0.z,a0.w,a1.x,a1.y,a1.z,a1.w};
      float bv[8] = {b0.x,b0.y,b0.z,b0.w,b1.x,b1.y,b1.z,b1.w};
      #pragma unroll
      for (int rr = 0; rr < 8; ++rr)
        #pragma unroll
        for (int qq = 0; qq < 8; ++qq)
          acc[rr*8+qq] = fmaf(av[rr], bv[qq], acc[rr*8+qq]);
    }
  }
  #pragma unroll
  for (int rr = 0; rr < 8; ++rr) {
    int row = ty*8 + rr;
    size_t obase = ((size_t)z*128 + row)*128;
    *(float4*)&cvd_out[obase + tx*4] =
        make_float4(acc[rr*8+0],acc[rr*8+1],acc[rr*8+2],acc[rr*8+3]);
    *(float4*)&cvd_out[obase + 64 + tx*4] =
        make_float4(acc[rr*8+4],acc[rr*8+5],acc[rr*8+6],acc[rr*8+7]);
  }
}

// ---------------- Sinkhorn: row stripes cached in VGPRs ----------------------
// E never changes across iterations. Thread (j=t&255, c=t>>8) caches its
// rowsum stripe (quads bk≡c mod 4 of row j, ≤16 float4) in registers after
// build; rowsum + epilogue never touch pE in LDS. Colsum (waves 0-7,
// rows i≡g mod 8, lane=column-quad) is the only remaining triangle stream.
// amdgpu_waves_per_eu(4,4): LDS (144 KB) forces 1 block/CU = 4 waves/EU;
// pin it so the allocator uses the full 128-VGPR budget instead of spilling
// eR to scratch while chasing an unreachable 8-waves/EU occupancy (R5 bug:
// WRITE_SIZE 61 MB of spill traffic).
__global__ __launch_bounds__(1024)
__attribute__((amdgpu_waves_per_eu(4, 4)))
void sink_kernel(const float* __restrict__ cvg, float* __restrict__ out) {
  extern __shared__ float pE[];                 // TRI2_TOT floats
  __shared__ __align__(16) float eu[260];
  __shared__ __align__(16) float ev[260];
  __shared__ __align__(16) float buf[8][256];
  __shared__ float vbS[256];
  __shared__ float redbufU[4], redbufV[4], redbuf8[8];
  __shared__ float Msh;
  const int t = threadIdx.x;
  const int z = blockIdx.x;
  const float* cvS = cvg + (size_t)z * 65536;

  if (t >= 512 && t < 768) eu[t-512] = 1.f;
  if (t == 768) eu[256] = 1.f;

  // ---- pass 1: masked slice max (waves 0-7) ----
  if (t < 512) {
    const int g = t >> 6, lane = t & 63, c0 = 4*(t & 63);
    float mx = 0.f;
    for (int mq = 0; mq < 32; ++mq) {
      int i = 8*mq + g;
      if (lane <= (i >> 2)) {
        float4 v = *(const float4*)&cvS[i*256 + c0];
        if (c0     <= i) mx = fmaxf(mx, v.x);
        if (c0 + 1 <= i) mx = fmaxf(mx, v.y);
        if (c0 + 2 <= i) mx = fmaxf(mx, v.z);
        if (c0 + 3 <= i) mx = fmaxf(mx, v.w);
      }
    }
    #pragma unroll
    for (int mm = 32; mm; mm >>= 1) mx = fmaxf(mx, __shfl_xor(mx, mm, 64));
    if (lane == 0) redbuf8[g] = mx;
  }
  __syncthreads();
  if (t == 0) {
    float m2 = redbuf8[0];
    #pragma unroll
    for (int q = 1; q < 8; ++q) m2 = fmaxf(m2, redbuf8[q]);
    Msh = m2;
  }
  __syncthreads();
  const float M = Msh;
  const float enM = __expf(-M);

  // ---- pass 2: build packed triangle (waves 0-7), b128 writes ----
  if (t < 512) {
    const int g = t >> 6, lane = t & 63, c0 = 4*(t & 63);
    for (int mq = 0; mq < 32; ++mq) {
      int i = 8*mq + g;
      if (lane <= (i >> 2)) {
        int rs = S_of(i);
        float4 v = *(const float4*)&cvS[i*256 + c0];
        float4 e;
        e.x = (c0     <= i) ? __expf(v.x - M) : 0.f;
        e.y = (c0 + 1 <= i) ? __expf(v.y - M) : 0.f;
        e.z = (c0 + 2 <= i) ? __expf(v.z - M) : 0.f;
        e.w = (c0 + 3 <= i) ? __expf(v.w - M) : 0.f;
        *(float4*)&pE[rs + c0] = e;
      }
    }
  }
  __syncthreads();

  const int j = t & 255;
  const int c = t >> 8;
  const int rsR = S_of(j);
  const int nb = (j >> 2) + 1;

  // ---- cache this thread's rowsum stripe in registers (zero-fill OOB) ----
  float4 eR[16];
  #pragma unroll
  for (int r = 0; r < 16; ++r) {
    int bk = c + 4*r;
    eR[r] = (bk < nb) ? *(const float4*)&pE[rsR + 4*bk]
                      : make_float4(0.f, 0.f, 0.f, 0.f);
  }

  for (int it = 0; it < 8; ++it) {
    // ---- phase A: colsum partials (waves 0-7) + S_eu reduce (waves 8-11) ---
    if (t < 512) {
      const int g = t >> 6, lane = t & 63, c0 = 4*(t & 63);
      float4 a = make_float4(0.f, 0.f, 0.f, 0.f);
      #pragma unroll 2
      for (int mq = 0; mq < 32; mq += 2) {
        int i0 = 8*mq + g, i1 = i0 + 8;
        float u0 = eu[i0], u1 = eu[i1];
        int rs0 = S_of(i0), rs1 = S_of(i1);
        if (lane <= (i0 >> 2)) {
          float4 e = *(const float4*)&pE[rs0 + c0];
          a.x = fmaf(e.x, u0, a.x); a.y = fmaf(e.y, u0, a.y);
          a.z = fmaf(e.z, u0, a.z); a.w = fmaf(e.w, u0, a.w);
        }
        if (lane <= (i1 >> 2)) {
          float4 e = *(const float4*)&pE[rs1 + c0];
          a.x = fmaf(e.x, u1, a.x); a.y = fmaf(e.y, u1, a.y);
          a.z = fmaf(e.z, u1, a.z); a.w = fmaf(e.w, u1, a.w);
        }
      }
      *(float4*)&buf[g][c0] = a;
    } else if (t < 768) {
      int tt = t - 512;
      float s = eu[tt];
      #pragma unroll
      for (int mm = 32; mm; mm >>= 1) s += __shfl_xor(s, mm, 64);
      if ((tt & 63) == 0) redbufU[tt >> 6] = s;
    }
    __syncthreads();
    // ---- phase B: ev from column sums; reduce S_ev; pad ev[256] ----
    if (t < 256) {
      float cj = ((buf[0][t] + buf[1][t]) + (buf[2][t] + buf[3][t]))
               + ((buf[4][t] + buf[5][t]) + (buf[6][t] + buf[7][t]))
               + enM * eu[256];
      float evt = NU_C / cj;
      ev[t] = evt;
      float s = evt;
      #pragma unroll
      for (int mm = 32; mm; mm >>= 1) s += __shfl_xor(s, mm, 64);
      if ((t & 63) == 0) redbufV[t >> 6] = s;
    } else if (t == 960) {
      float S = ((redbufU[0] + redbufU[1]) + (redbufU[2] + redbufU[3])) + eu[256];
      ev[256] = 0.5f / (enM * S);
    }
    __syncthreads();
    // ---- phase C: rowsum partials from registers (all 16 waves) ----
    {
      float r0 = 0.f, r1 = 0.f, r2 = 0.f, r3 = 0.f;
      #pragma unroll
      for (int r = 0; r < 16; ++r) {
        int bk = c + 4*r;
        float4 ev4 = *(const float4*)&ev[4*bk & 1023];
        r0 = fmaf(eR[r].x, ev4.x, r0);
        r1 = fmaf(eR[r].y, ev4.y, r1);
        r2 = fmaf(eR[r].z, ev4.z, r2);
        r3 = fmaf(eR[r].w, ev4.w, r3);
      }
      buf[c][j] = (r0 + r1) + (r2 + r3);
    }
    __syncthreads();
    // ---- phase D: eu from row sums; pad eu[256] ----
    if (t < 256) {
      float ri = ((buf[0][t] + buf[1][t]) + (buf[2][t] + buf[3][t]))
               + enM * ev[256];
      eu[t] = MU_C / ri;
    } else if (t == 960) {
      float S = ((redbufV[0] + redbufV[1]) + (redbufV[2] + redbufV[3])) + ev[256];
      eu[256] = 0.5f / (enM * S);
    }
    __syncthreads();
  }

  // ---- epilogue: occ / first-max argmax / conf / corr (from registers) ----
  {
    float occ = 0.f, vmax = -1.f;
    int jm = 1 << 30;
    #pragma unroll
    for (int r = 0; r < 16; ++r) {
      int bk = c + 4*r;
      float4 ev4 = *(const float4*)&ev[4*bk & 1023];
      float p0 = eR[r].x*ev4.x, p1 = eR[r].y*ev4.y,
            p2 = eR[r].z*ev4.z, p3 = eR[r].w*ev4.w;
      occ += (p0 + p1) + (p2 + p3);
      if (p0 > vmax) { vmax = p0; jm = 4*bk;   }
      if (p1 > vmax) { vmax = p1; jm = 4*bk+1; }
      if (p2 > vmax) { vmax = p2; jm = 4*bk+2; }
      if (p3 > vmax) { vmax = p3; jm = 4*bk+3; }
    }
    buf[c][j] = occ;                        // phase A': occ partials
    __syncthreads();
    if (t < 256) {
      float occT = ((buf[0][t] + buf[1][t]) + (buf[2][t] + buf[3][t]));
      out[OCC_OFF + z*256 + t] = occT * eu[t] * 512.f;
    }
    __syncthreads();
    buf[c][j] = vmax;                       // phase B': vmax partials
    __syncthreads();
    if (t < 256)
      vbS[t] = fmaxf(fmaxf(buf[0][t], buf[1][t]), fmaxf(buf[2][t], buf[3][t]));
    __syncthreads();
    ((int*)buf)[c*256 + j] = (vmax == vbS[j]) ? jm : (1 << 30);  // phase C'
    __syncthreads();
    if (t < 256) {
      const int* bi = (const int*)buf;
      int jb = min(min(bi[t], bi[256 + t]), min(bi[512 + t], bi[768 + t]));
      const int rsT = S_of(t);
      const float sc = eu[t] * 512.f;
      float conf = 0.f, corr = 0.f;
      #pragma unroll
      for (int d = 0; d < 5; ++d) {
        int jp = jb + d - 2;
        float wgt = 0.f;
        if (jp >= 0 && jp <= t) wgt = pE[rsT + jp] * ev[jp] * sc;
        conf += wgt;
        corr = fmaf(wgt, (float)jp, corr);
      }
      corr = (corr + 1e-4f) / (conf + 1e-4f);
      out[DISP_OFF + z*256 + t] = (float)t - corr;
      out[CONF_OFF + z*256 + t] = conf;
    }
  }
}

extern "C" void kernel_launch(void* const* d_in, const int* in_sizes, int n_in,
                              void* d_out, int out_size, void* d_ws, size_t ws_size,
                              hipStream_t stream) {
  (void)in_sizes; (void)n_in; (void)out_size; (void)d_ws; (void)ws_size;
  const float* feat = (const float*)d_in[0];
  const float* lnw  = (const float*)d_in[1];
  const float* lnb  = (const float*)d_in[2];
  float* out = (float*)d_out;

  (void)hipFuncSetAttribute((const void*)cv_kernel,
                            hipFuncAttributeMaxDynamicSharedMemorySize, 65536);
  (void)hipFuncSetAttribute((const void*)cvd_kernel,
                            hipFuncAttributeMaxDynamicSharedMemorySize, 65536);
  (void)hipFuncSetAttribute((const void*)sink_kernel,
                            hipFuncAttributeMaxDynamicSharedMemorySize, TRI2_TOT*4);

  cv_kernel<<<dim3(2, 2, NSL), 256, 65536, stream>>>(feat, lnw, lnb, out + CV_OFF);
  sink_kernel<<<dim3(NSL), 1024, TRI2_TOT*4, stream>>>(out + CV_OFF, out);
  cvd_kernel<<<dim3(160), 256, 65536, stream>>>(feat, lnw, lnb, out + CVD_OFF);
}